// Round 16
// baseline (498.022 us; speedup 1.0000x reference)
//
#include <hip/hip_runtime.h>
#include <hip/hip_fp16.h>

#define MAXD 192
#define NCH  16

#define RFL_I(x) __builtin_amdgcn_readfirstlane(x)
#define RFL_F(x) __int_as_float(__builtin_amdgcn_readfirstlane(__float_as_int(x)))
#define RDLU(v,k) ((unsigned)__builtin_amdgcn_readlane((int)(v), (k)))
#define H2(u) __builtin_bit_cast(__half2, (unsigned)(u))
#define U32(h) __builtin_bit_cast(unsigned, (h))

struct F2 { float x, y; };   // align 4: dword-aligned global pair load
#define LOADF2(base, boff) (*(const F2*)((base) + (boff)))

// One block per (level j = blockIdx.x, point n = blockIdx.y) — XCD = j,
// each XCD reads one level pair (~7.9 MB working set).
// Waves 0-2: pass-1 (scale 1) disparity chunks [0,64),[64,128),[128,192).
// Wave 3:   pass-0 (scale 4, D=48), level j+8.
// Wave-private LDS strips; only block-wide barrier is the val4 handoff.
// R16: strip row loop FULLY UNROLLED so the scheduler batches all 20
// dwordx2 loads before the first vmcnt wait (exposed VMEM latencies per
// iteration drop ~6 -> ~2); paired with __launch_bounds__(256,6) so the
// ~40 VGPRs of in-flight load data fit without spilling (R9's failure was
// this unroll at the 64-VGPR cap of (256,8)).
// Packed half2 strip (2 ch/iter), pk-f16 taps, pair-loads, folded weights.
// LESSON: WRITE_SIZE is the spill tripwire (must stay ~49 MB).
__global__ __launch_bounds__(256, 6) void pbm_kernel(
    const float* __restrict__ lfeat,   // (16,1,16,H,W)
    const float* __restrict__ rfeat,
    const float* __restrict__ points,  // (1,N,2)
    const int* __restrict__ pW, const int* __restrict__ pH,
    float* __restrict__ out)           // (1,N,192,8)
{
    const int W = RFL_I(*pW), H = RFL_I(*pH);
    const int HW = W * H;
    const int j   = blockIdx.x;        // XCD = j
    const int n   = blockIdx.y;
    const int tid = threadIdx.x;
    const int wv  = tid >> 6;
    const int l   = tid & 63;

    const float pxr = points[2 * n];
    const float pyr = points[2 * n + 1];
    const float pxf = floorf(pxr), pyf = floorf(pyr);
    const float fx  = RFL_F(pxr - pxf);
    const float fy  = RFL_F(pyr - pyf);
    const int   x0i = RFL_I((int)pxf);
    const int   y0i = RFL_I((int)pyf);

    __shared__ unsigned svh[4][5][68]; // per-wave right strip, half2 (2 ch packed)
    __shared__ float    val4[48];

    const bool isP0   = (wv == 3);
    const int  s_     = RFL_I(isP0 ? 4 : 1);
    const int  lvl    = RFL_I(isP0 ? j + 8 : j);
    const int  off    = RFL_I(isP0 ? 49 : wv * 64 + 65);
    const int  DC     = RFL_I(isP0 ? 48 : 64);
    const int  stageN = RFL_I(isP0 ? 52 : 64);

    // ---- strip column constants (col == lane): pair offset + folded weights
    const int   cx    = x0i + s_ * (l - off);
    const int   pairB = min(max(cx, 0), W - 2) * 4;
    const float ax0   = (((unsigned)cx       < (unsigned)W) ? 1.0f : 0.0f) * (1.0f - fx);
    const float ax1   = (((unsigned)(cx + 1) < (unsigned)W) ? 1.0f : 0.0f) * fx;
    const float w0    = ((cx >= W - 1) ? 0.f : ax0) + ((cx >= 0) ? 0.f : ax1);
    const float w1    = ((cx >= W - 1) ? ax0 : 0.f) + ((cx >= 0) ? ax1 : 0.f);

    // ---- cleanup taps (pass-1 waves, lanes<20): col 64+(l&3), row l>>2 ----
    const int   dyc  = min(l >> 2, 4);
    const int   dcol = 64 + (l & 3);
    const int   dcx  = x0i + s_ * (dcol - off);
    const float dax0 = (((unsigned)dcx       < (unsigned)W) ? 1.0f : 0.0f) * (1.0f - fx);
    const float dax1 = (((unsigned)(dcx + 1) < (unsigned)W) ? 1.0f : 0.0f) * fx;
    const float w0d  = ((dcx >= W - 1) ? 0.f : dax0) + ((dcx >= 0) ? 0.f : dax1);
    const float w1d  = ((dcx >= W - 1) ? dax0 : 0.f) + ((dcx >= 0) ? dax1 : 0.f);
    const int   dyr  = y0i + s_ * (dyc - 2);
    const int   voA  = min(max(dyr, 0), H - 1) * (W * 4) + min(max(dcx, 0), W - 2) * 4;
    const int   voB  = min(max(dyr + 1, 0), H - 1) * (W * 4) + min(max(dcx, 0), W - 2) * 4;
    const float dwy0 = ((unsigned)dyr       < (unsigned)H) ? (1.0f - fy) : 0.0f;
    const float dwy1 = ((unsigned)(dyr + 1) < (unsigned)H) ? fy : 0.0f;

    // ---- left window taps (lanes 0..24 meaningful) ----
    const int   lq   = min(l, 24);
    const int   lyy  = lq / 5;
    const int   lxx  = lq - lyy * 5;
    const int   lx   = x0i + s_ * (lxx - 2);
    const int   ly   = y0i + s_ * (lyy - 2);
    const float lax0 = (((unsigned)lx       < (unsigned)W) ? 1.0f : 0.0f) * (1.0f - fx);
    const float lax1 = (((unsigned)(lx + 1) < (unsigned)W) ? 1.0f : 0.0f) * fx;
    const float w0l  = ((lx >= W - 1) ? 0.f : lax0) + ((lx >= 0) ? 0.f : lax1);
    const float w1l  = ((lx >= W - 1) ? lax0 : 0.f) + ((lx >= 0) ? lax1 : 0.f);
    const int   loA  = min(max(ly, 0), H - 1) * (W * 4) + min(max(lx, 0), W - 2) * 4;
    const int   loB  = min(max(ly + 1, 0), H - 1) * (W * 4) + min(max(lx, 0), W - 2) * 4;
    const float lwy0 = ((unsigned)ly       < (unsigned)H) ? (1.0f - fy) : 0.0f;
    const float lwy1 = ((unsigned)(ly + 1) < (unsigned)H) ? fy : 0.0f;

    const char* RbC = (const char*)(rfeat + (size_t)(lvl * NCH) * HW);
    const char* LbC = (const char*)(lfeat + (size_t)(lvl * NCH) * HW);

    float acc = 0.0f;
#pragma unroll 1
    for (int c = 0; c < NCH; c += 2) {
        const char* RpC0 = RbC + (size_t)c * HW * 4;
        const char* RpC1 = RpC0 + (size_t)HW * 4;
        const char* LpC0 = LbC + (size_t)c * HW * 4;
        const char* LpC1 = LpC0 + (size_t)HW * 4;

        if (l < stageN) {
#pragma unroll
            for (int yy = 0; yy < 5; ++yy) {
                int   yr   = y0i + s_ * (yy - 2);          // uniform -> SALU
                int   rbB0 = min(max(yr, 0), H - 1) * (W * 4);
                int   rbB1 = min(max(yr + 1, 0), H - 1) * (W * 4);
                float wy0  = ((unsigned)yr       < (unsigned)H) ? (1.0f - fy) : 0.0f;
                float wy1  = ((unsigned)(yr + 1) < (unsigned)H) ? fy : 0.0f;
                F2 a0 = LOADF2(RpC0 + rbB0, pairB);
                F2 b0 = LOADF2(RpC0 + rbB1, pairB);
                F2 a1 = LOADF2(RpC1 + rbB0, pairB);
                F2 b1 = LOADF2(RpC1 + rbB1, pairB);
                float h00 = fmaf(w0, a0.x, w1 * a0.y);
                float h01 = fmaf(w0, b0.x, w1 * b0.y);
                float h10 = fmaf(w0, a1.x, w1 * a1.y);
                float h11 = fmaf(w0, b1.x, w1 * b1.y);
                float rx = fmaf(wy0, h00, wy1 * h01);
                float ry = fmaf(wy0, h10, wy1 * h11);
                svh[wv][yy][l] = U32(__floats2half2_rn(rx, ry));
            }
        }
        if (!isP0 && l < 20) {
            F2 pa0 = LOADF2(RpC0, voA);
            F2 pb0 = LOADF2(RpC0, voB);
            F2 pa1 = LOADF2(RpC1, voA);
            F2 pb1 = LOADF2(RpC1, voB);
            float h00 = fmaf(w0d, pa0.x, w1d * pa0.y);
            float h01 = fmaf(w0d, pb0.x, w1d * pb0.y);
            float h10 = fmaf(w0d, pa1.x, w1d * pa1.y);
            float h11 = fmaf(w0d, pb1.x, w1d * pb1.y);
            float rx = fmaf(dwy0, h00, dwy1 * h01);
            float ry = fmaf(dwy0, h10, dwy1 * h11);
            svh[wv][dyc][dcol] = U32(__floats2half2_rn(rx, ry));
        }
        unsigned lpk;
        {
            F2 pa0 = LOADF2(LpC0, loA);
            F2 pb0 = LOADF2(LpC0, loB);
            F2 pa1 = LOADF2(LpC1, loA);
            F2 pb1 = LOADF2(LpC1, loB);
            float h00 = fmaf(w0l, pa0.x, w1l * pa0.y);
            float h01 = fmaf(w0l, pb0.x, w1l * pb0.y);
            float h10 = fmaf(w0l, pa1.x, w1l * pa1.y);
            float h11 = fmaf(w0l, pb1.x, w1l * pb1.y);
            float lval0 = fmaf(lwy0, h00, lwy1 * h01);
            float lval1 = fmaf(lwy0, h10, lwy1 * h11);
            lpk = U32(__floats2half2_rn(lval0, lval1));
        }

        if (l < DC) {
            __half2 aE = __floats2half2_rn(0.f, 0.f);
            __half2 aO = __floats2half2_rn(0.f, 0.f);
#define TAPROW(YY) {                                                        \
            const unsigned* rp = &svh[wv][YY][DC - 1 - l];                  \
            unsigned q0 = rp[0], q1 = rp[1], q2 = rp[2], q3 = rp[3], q4 = rp[4];\
            unsigned s0 = RDLU(lpk, (YY)*5+0);                              \
            unsigned s1 = RDLU(lpk, (YY)*5+1);                              \
            unsigned s2 = RDLU(lpk, (YY)*5+2);                              \
            unsigned s3 = RDLU(lpk, (YY)*5+3);                              \
            unsigned s4 = RDLU(lpk, (YY)*5+4);                              \
            aE = __hadd2(aE, __habs2(__hsub2(H2(s0), H2(q0))));             \
            aO = __hadd2(aO, __habs2(__hsub2(H2(s1), H2(q1))));             \
            aE = __hadd2(aE, __habs2(__hsub2(H2(s2), H2(q2))));             \
            aO = __hadd2(aO, __habs2(__hsub2(H2(s3), H2(q3))));             \
            aE = __hadd2(aE, __habs2(__hsub2(H2(s4), H2(q4)))); }
            TAPROW(0)
            TAPROW(1)
            TAPROW(2)
            TAPROW(3)
            TAPROW(4)
#undef TAPROW
            __half2 at = __hadd2(aE, aO);
            acc += __half2float(__low2half(at)) + __half2float(__high2half(at));
        }
    }

    if (isP0 && l < 48)
        val4[l] = 1.0f - expf(-acc * (1.0f / 400.0f));

    __syncthreads();                     // the ONLY block-wide barrier

    if (tid < MAXD) {                    // waves 0-2: d == tid
        float v1  = 1.0f - expf(-acc * (1.0f / 400.0f));
        float pos = (float)tid * (47.0f / 191.0f);
        float i0f = floorf(pos);
        int   i0  = (int)i0f;
        float w   = pos - i0f;
        int   i1  = min(i0 + 1, 47);
        float up  = val4[i0] + w * (val4[i1] - val4[i0]);
        out[((size_t)n * MAXD + tid) * 8 + j] = v1 + up;
    }
}

extern "C" void kernel_launch(void* const* d_in, const int* in_sizes, int n_in,
                              void* d_out, int out_size, void* d_ws, size_t ws_size,
                              hipStream_t stream) {
    const float* lf  = (const float*)d_in[0];
    const float* rf  = (const float*)d_in[1];
    const float* pts = (const float*)d_in[2];
    const int*   pW  = (const int*)d_in[3];
    const int*   pH  = (const int*)d_in[4];
    float* out = (float*)d_out;

    const int N = in_sizes[2] / 2;       // (B=1, N, 2)
    pbm_kernel<<<dim3(8, N), 256, 0, stream>>>(lf, rf, pts, pW, pH, out);
}

// Round 17
// 206.063 us; speedup vs baseline: 2.4168x; 2.4168x over previous
//
#include <hip/hip_runtime.h>
#include <hip/hip_fp16.h>

#define MAXD 192
#define NCH  16

#define RFL_I(x) __builtin_amdgcn_readfirstlane(x)
#define RFL_F(x) __int_as_float(__builtin_amdgcn_readfirstlane(__float_as_int(x)))
#define RDLU(v,k) ((unsigned)__builtin_amdgcn_readlane((int)(v), (k)))
#define H2(u) __builtin_bit_cast(__half2, (unsigned)(u))
#define U32(h) __builtin_bit_cast(unsigned, (h))

struct F2 { float x, y; };   // align 4: dword-aligned global pair load
#define LOADF2(base, boff) (*(const F2*)((base) + (boff)))

// One block per (level j = blockIdx.x, point n = blockIdx.y) — XCD = j.
// 512 threads = 8 waves; channels split in HALVES across waves so each
// wave's serial chain is 4 channel-pair iterations instead of 8 (R17: the
// latency chain halves via wave-parallelism — the axis the register
// allocator can't sabotage; R9/R14/R16 proved register pipelining spills).
//   waves 0-5: pass-1 (scale 1), chunk = wv%3 -> disparities [chunk*64, +64),
//              channel half = wv/3 (channels 8h..8h+7).
//   waves 6-7: pass-0 (scale 4, D=48), level j+8, channel half = wv-6.
// Wave-private LDS strips; ONE block-wide barrier before the epilogue
// combines the two channel-half partials (LDS part arrays) and upsamples.
// Packed half2 strip (2 ch/iter), pk-f16 taps, pair-loads, folded weights.
// LESSON: no long-lived register arrays, no unrolling; recompute row
// constants inline; WRITE_SIZE = spill tripwire (~49 MB).
__global__ __launch_bounds__(512, 8) void pbm_kernel(
    const float* __restrict__ lfeat,   // (16,1,16,H,W)
    const float* __restrict__ rfeat,
    const float* __restrict__ points,  // (1,N,2)
    const int* __restrict__ pW, const int* __restrict__ pH,
    float* __restrict__ out)           // (1,N,192,8)
{
    const int W = RFL_I(*pW), H = RFL_I(*pH);
    const int HW = W * H;
    const int j   = blockIdx.x;        // XCD = j
    const int n   = blockIdx.y;
    const int tid = threadIdx.x;
    const int wv  = tid >> 6;
    const int l   = tid & 63;

    const float pxr = points[2 * n];
    const float pyr = points[2 * n + 1];
    const float pxf = floorf(pxr), pyf = floorf(pyr);
    const float fx  = RFL_F(pxr - pxf);
    const float fy  = RFL_F(pyr - pyf);
    const int   x0i = RFL_I((int)pxf);
    const int   y0i = RFL_I((int)pyf);

    __shared__ unsigned svh[8][5][68]; // per-wave right strip, half2 (2 ch packed)
    __shared__ float    part1[3][2][64];
    __shared__ float    part4[2][48];

    const bool isP0   = (wv >= 6);
    const int  chunk  = RFL_I(isP0 ? 0 : (wv % 3));
    const int  half   = RFL_I(isP0 ? (wv - 6) : (wv / 3));
    const int  s_     = RFL_I(isP0 ? 4 : 1);
    const int  lvl    = RFL_I(isP0 ? j + 8 : j);
    const int  off    = RFL_I(isP0 ? 49 : chunk * 64 + 65);
    const int  DC     = RFL_I(isP0 ? 48 : 64);
    const int  stageN = RFL_I(isP0 ? 52 : 64);
    const int  cstart = RFL_I(half * 8);

    // ---- strip column constants (col == lane): pair offset + folded weights
    const int   cx    = x0i + s_ * (l - off);
    const int   pairB = min(max(cx, 0), W - 2) * 4;
    const float ax0   = (((unsigned)cx       < (unsigned)W) ? 1.0f : 0.0f) * (1.0f - fx);
    const float ax1   = (((unsigned)(cx + 1) < (unsigned)W) ? 1.0f : 0.0f) * fx;
    const float w0    = ((cx >= W - 1) ? 0.f : ax0) + ((cx >= 0) ? 0.f : ax1);
    const float w1    = ((cx >= W - 1) ? ax0 : 0.f) + ((cx >= 0) ? ax1 : 0.f);

    // ---- cleanup taps (pass-1 waves, lanes<20): col 64+(l&3), row l>>2 ----
    const int   dyc  = min(l >> 2, 4);
    const int   dcol = 64 + (l & 3);
    const int   dcx  = x0i + s_ * (dcol - off);
    const float dax0 = (((unsigned)dcx       < (unsigned)W) ? 1.0f : 0.0f) * (1.0f - fx);
    const float dax1 = (((unsigned)(dcx + 1) < (unsigned)W) ? 1.0f : 0.0f) * fx;
    const float w0d  = ((dcx >= W - 1) ? 0.f : dax0) + ((dcx >= 0) ? 0.f : dax1);
    const float w1d  = ((dcx >= W - 1) ? dax0 : 0.f) + ((dcx >= 0) ? dax1 : 0.f);
    const int   dyr  = y0i + s_ * (dyc - 2);
    const int   voA  = min(max(dyr, 0), H - 1) * (W * 4) + min(max(dcx, 0), W - 2) * 4;
    const int   voB  = min(max(dyr + 1, 0), H - 1) * (W * 4) + min(max(dcx, 0), W - 2) * 4;
    const float dwy0 = ((unsigned)dyr       < (unsigned)H) ? (1.0f - fy) : 0.0f;
    const float dwy1 = ((unsigned)(dyr + 1) < (unsigned)H) ? fy : 0.0f;

    // ---- left window taps (lanes 0..24 meaningful) ----
    const int   lq   = min(l, 24);
    const int   lyy  = lq / 5;
    const int   lxx  = lq - lyy * 5;
    const int   lx   = x0i + s_ * (lxx - 2);
    const int   ly   = y0i + s_ * (lyy - 2);
    const float lax0 = (((unsigned)lx       < (unsigned)W) ? 1.0f : 0.0f) * (1.0f - fx);
    const float lax1 = (((unsigned)(lx + 1) < (unsigned)W) ? 1.0f : 0.0f) * fx;
    const float w0l  = ((lx >= W - 1) ? 0.f : lax0) + ((lx >= 0) ? 0.f : lax1);
    const float w1l  = ((lx >= W - 1) ? lax0 : 0.f) + ((lx >= 0) ? lax1 : 0.f);
    const int   loA  = min(max(ly, 0), H - 1) * (W * 4) + min(max(lx, 0), W - 2) * 4;
    const int   loB  = min(max(ly + 1, 0), H - 1) * (W * 4) + min(max(lx, 0), W - 2) * 4;
    const float lwy0 = ((unsigned)ly       < (unsigned)H) ? (1.0f - fy) : 0.0f;
    const float lwy1 = ((unsigned)(ly + 1) < (unsigned)H) ? fy : 0.0f;

    const char* RbC = (const char*)(rfeat + (size_t)(lvl * NCH) * HW);
    const char* LbC = (const char*)(lfeat + (size_t)(lvl * NCH) * HW);

    float acc = 0.0f;
#pragma unroll 1
    for (int ci = 0; ci < 4; ++ci) {
        const int c = cstart + 2 * ci;
        const char* RpC0 = RbC + (size_t)c * HW * 4;
        const char* RpC1 = RpC0 + (size_t)HW * 4;
        const char* LpC0 = LbC + (size_t)c * HW * 4;
        const char* LpC1 = LpC0 + (size_t)HW * 4;

        if (l < stageN) {
#pragma unroll 1
            for (int yy = 0; yy < 5; ++yy) {
                int   yr   = y0i + s_ * (yy - 2);          // uniform -> SALU
                int   rbB0 = min(max(yr, 0), H - 1) * (W * 4);
                int   rbB1 = min(max(yr + 1, 0), H - 1) * (W * 4);
                float wy0  = ((unsigned)yr       < (unsigned)H) ? (1.0f - fy) : 0.0f;
                float wy1  = ((unsigned)(yr + 1) < (unsigned)H) ? fy : 0.0f;
                F2 a0 = LOADF2(RpC0 + rbB0, pairB);
                F2 b0 = LOADF2(RpC0 + rbB1, pairB);
                F2 a1 = LOADF2(RpC1 + rbB0, pairB);
                F2 b1 = LOADF2(RpC1 + rbB1, pairB);
                float h00 = fmaf(w0, a0.x, w1 * a0.y);
                float h01 = fmaf(w0, b0.x, w1 * b0.y);
                float h10 = fmaf(w0, a1.x, w1 * a1.y);
                float h11 = fmaf(w0, b1.x, w1 * b1.y);
                float rx = fmaf(wy0, h00, wy1 * h01);
                float ry = fmaf(wy0, h10, wy1 * h11);
                svh[wv][yy][l] = U32(__floats2half2_rn(rx, ry));
            }
        }
        if (!isP0 && l < 20) {
            F2 pa0 = LOADF2(RpC0, voA);
            F2 pb0 = LOADF2(RpC0, voB);
            F2 pa1 = LOADF2(RpC1, voA);
            F2 pb1 = LOADF2(RpC1, voB);
            float h00 = fmaf(w0d, pa0.x, w1d * pa0.y);
            float h01 = fmaf(w0d, pb0.x, w1d * pb0.y);
            float h10 = fmaf(w0d, pa1.x, w1d * pa1.y);
            float h11 = fmaf(w0d, pb1.x, w1d * pb1.y);
            float rx = fmaf(dwy0, h00, dwy1 * h01);
            float ry = fmaf(dwy0, h10, dwy1 * h11);
            svh[wv][dyc][dcol] = U32(__floats2half2_rn(rx, ry));
        }
        unsigned lpk;
        {
            F2 pa0 = LOADF2(LpC0, loA);
            F2 pb0 = LOADF2(LpC0, loB);
            F2 pa1 = LOADF2(LpC1, loA);
            F2 pb1 = LOADF2(LpC1, loB);
            float h00 = fmaf(w0l, pa0.x, w1l * pa0.y);
            float h01 = fmaf(w0l, pb0.x, w1l * pb0.y);
            float h10 = fmaf(w0l, pa1.x, w1l * pa1.y);
            float h11 = fmaf(w0l, pb1.x, w1l * pb1.y);
            float lval0 = fmaf(lwy0, h00, lwy1 * h01);
            float lval1 = fmaf(lwy0, h10, lwy1 * h11);
            lpk = U32(__floats2half2_rn(lval0, lval1));
        }

        if (l < DC) {
            __half2 aE = __floats2half2_rn(0.f, 0.f);
            __half2 aO = __floats2half2_rn(0.f, 0.f);
#define TAPROW(YY) {                                                        \
            const unsigned* rp = &svh[wv][YY][DC - 1 - l];                  \
            unsigned q0 = rp[0], q1 = rp[1], q2 = rp[2], q3 = rp[3], q4 = rp[4];\
            unsigned s0 = RDLU(lpk, (YY)*5+0);                              \
            unsigned s1 = RDLU(lpk, (YY)*5+1);                              \
            unsigned s2 = RDLU(lpk, (YY)*5+2);                              \
            unsigned s3 = RDLU(lpk, (YY)*5+3);                              \
            unsigned s4 = RDLU(lpk, (YY)*5+4);                              \
            aE = __hadd2(aE, __habs2(__hsub2(H2(s0), H2(q0))));             \
            aO = __hadd2(aO, __habs2(__hsub2(H2(s1), H2(q1))));             \
            aE = __hadd2(aE, __habs2(__hsub2(H2(s2), H2(q2))));             \
            aO = __hadd2(aO, __habs2(__hsub2(H2(s3), H2(q3))));             \
            aE = __hadd2(aE, __habs2(__hsub2(H2(s4), H2(q4)))); }
            TAPROW(0)
            TAPROW(1)
            TAPROW(2)
            TAPROW(3)
            TAPROW(4)
#undef TAPROW
            __half2 at = __hadd2(aE, aO);
            acc += __half2float(__low2half(at)) + __half2float(__high2half(at));
        }
    }

    // write per-wave partials (channel halves)
    if (isP0) {
        if (l < 48) part4[half][l] = acc;
    } else {
        part1[chunk][half][l] = acc;
    }

    __syncthreads();                     // the ONLY block-wide barrier

    if (tid < MAXD) {                    // d == tid
        const int ch = tid >> 6, ll = tid & 63;
        float s1 = part1[ch][0][ll] + part1[ch][1][ll];
        float v1 = 1.0f - expf(-s1 * (1.0f / 400.0f));
        float pos = (float)tid * (47.0f / 191.0f);
        float i0f = floorf(pos);
        int   i0  = (int)i0f;
        float w   = pos - i0f;
        int   i1  = min(i0 + 1, 47);
        float s40 = part4[0][i0] + part4[1][i0];
        float s41 = part4[0][i1] + part4[1][i1];
        float v40 = 1.0f - expf(-s40 * (1.0f / 400.0f));
        float v41 = 1.0f - expf(-s41 * (1.0f / 400.0f));
        out[((size_t)n * MAXD + tid) * 8 + j] = v1 + v40 + w * (v41 - v40);
    }
}

extern "C" void kernel_launch(void* const* d_in, const int* in_sizes, int n_in,
                              void* d_out, int out_size, void* d_ws, size_t ws_size,
                              hipStream_t stream) {
    const float* lf  = (const float*)d_in[0];
    const float* rf  = (const float*)d_in[1];
    const float* pts = (const float*)d_in[2];
    const int*   pW  = (const int*)d_in[3];
    const int*   pH  = (const int*)d_in[4];
    float* out = (float*)d_out;

    const int N = in_sizes[2] / 2;       // (B=1, N, 2)
    pbm_kernel<<<dim3(8, N), 512, 0, stream>>>(lf, rf, pts, pW, pH, out);
}

// Round 18
// 171.030 us; speedup vs baseline: 2.9119x; 1.2048x over previous
//
#include <hip/hip_runtime.h>
#include <hip/hip_fp16.h>

#define MAXD 192
#define NCH  16

#define RFL_I(x) __builtin_amdgcn_readfirstlane(x)
#define RFL_F(x) __int_as_float(__builtin_amdgcn_readfirstlane(__float_as_int(x)))
#define RDLU(v,k) ((unsigned)__builtin_amdgcn_readlane((int)(v), (k)))
#define H2(u) __builtin_bit_cast(__half2, (unsigned)(u))
#define U32(h) __builtin_bit_cast(unsigned, (h))

struct F2 { float x, y; };   // align 4: dword-aligned global pair load
#define LOADF2(base, boff) (*(const F2*)((base) + (boff)))

// One block per (level j = blockIdx.x, point n = blockIdx.y) — XCD = j.
// Waves 0-2: pass-1 (scale 1) disparity chunks [0,64),[64,128),[128,192).
// Wave 3:   pass-0 (scale 4, D=48), level j+8.
// Wave-private LDS strips; only block-wide barrier is the val4 handoff.
// R18: VMEM-ISSUE reduction. Evidence: R12 (VALU cut), R15 (L2 locality),
// R17 (latency-chain halving) were ALL flat at ~207 µs while VMEM instr
// count stayed constant — the kernel is bound on vector-memory instruction
// issue (TA). For pass-1 (s=1) strip rows share raw image rows: x-lerp
// each raw row ONCE into scalar h, carry h_prev (2 loop-carried VGPRs),
// y-lerp consecutive h pairs. Strip loads 20 -> 12 per 2-ch iteration
// (bit-identical math). Pass-0 (s=4, disjoint rows) keeps the old path.
// Packed half2 strip (2 ch/iter), pk-f16 taps, pair-loads, folded weights.
// LESSON: no big register arrays / no unrolling (spills); WRITE_SIZE is
// the spill tripwire (~49 MB).
__global__ __launch_bounds__(256, 8) void pbm_kernel(
    const float* __restrict__ lfeat,   // (16,1,16,H,W)
    const float* __restrict__ rfeat,
    const float* __restrict__ points,  // (1,N,2)
    const int* __restrict__ pW, const int* __restrict__ pH,
    float* __restrict__ out)           // (1,N,192,8)
{
    const int W = RFL_I(*pW), H = RFL_I(*pH);
    const int HW = W * H;
    const int j   = blockIdx.x;        // XCD = j
    const int n   = blockIdx.y;
    const int tid = threadIdx.x;
    const int wv  = tid >> 6;
    const int l   = tid & 63;

    const float pxr = points[2 * n];
    const float pyr = points[2 * n + 1];
    const float pxf = floorf(pxr), pyf = floorf(pyr);
    const float fx  = RFL_F(pxr - pxf);
    const float fy  = RFL_F(pyr - pyf);
    const int   x0i = RFL_I((int)pxf);
    const int   y0i = RFL_I((int)pyf);

    __shared__ unsigned svh[4][5][68]; // per-wave right strip, half2 (2 ch packed)
    __shared__ float    val4[48];

    const bool isP0   = (wv == 3);
    const int  s_     = RFL_I(isP0 ? 4 : 1);
    const int  lvl    = RFL_I(isP0 ? j + 8 : j);
    const int  off    = RFL_I(isP0 ? 49 : wv * 64 + 65);
    const int  DC     = RFL_I(isP0 ? 48 : 64);

    // ---- strip column constants (col == lane): pair offset + folded weights
    const int   cx    = x0i + s_ * (l - off);
    const int   pairB = min(max(cx, 0), W - 2) * 4;
    const float ax0   = (((unsigned)cx       < (unsigned)W) ? 1.0f : 0.0f) * (1.0f - fx);
    const float ax1   = (((unsigned)(cx + 1) < (unsigned)W) ? 1.0f : 0.0f) * fx;
    const float w0    = ((cx >= W - 1) ? 0.f : ax0) + ((cx >= 0) ? 0.f : ax1);
    const float w1    = ((cx >= W - 1) ? ax0 : 0.f) + ((cx >= 0) ? ax1 : 0.f);

    // ---- cleanup taps (pass-1 waves, lanes<20): col 64+(l&3), row l>>2 ----
    const int   dyc  = min(l >> 2, 4);
    const int   dcol = 64 + (l & 3);
    const int   dcx  = x0i + s_ * (dcol - off);
    const float dax0 = (((unsigned)dcx       < (unsigned)W) ? 1.0f : 0.0f) * (1.0f - fx);
    const float dax1 = (((unsigned)(dcx + 1) < (unsigned)W) ? 1.0f : 0.0f) * fx;
    const float w0d  = ((dcx >= W - 1) ? 0.f : dax0) + ((dcx >= 0) ? 0.f : dax1);
    const float w1d  = ((dcx >= W - 1) ? dax0 : 0.f) + ((dcx >= 0) ? dax1 : 0.f);
    const int   dyr  = y0i + s_ * (dyc - 2);
    const int   voA  = min(max(dyr, 0), H - 1) * (W * 4) + min(max(dcx, 0), W - 2) * 4;
    const int   voB  = min(max(dyr + 1, 0), H - 1) * (W * 4) + min(max(dcx, 0), W - 2) * 4;
    const float dwy0 = ((unsigned)dyr       < (unsigned)H) ? (1.0f - fy) : 0.0f;
    const float dwy1 = ((unsigned)(dyr + 1) < (unsigned)H) ? fy : 0.0f;

    // ---- left window taps (lanes 0..24 meaningful) ----
    const int   lq   = min(l, 24);
    const int   lyy  = lq / 5;
    const int   lxx  = lq - lyy * 5;
    const int   lx   = x0i + s_ * (lxx - 2);
    const int   ly   = y0i + s_ * (lyy - 2);
    const float lax0 = (((unsigned)lx       < (unsigned)W) ? 1.0f : 0.0f) * (1.0f - fx);
    const float lax1 = (((unsigned)(lx + 1) < (unsigned)W) ? 1.0f : 0.0f) * fx;
    const float w0l  = ((lx >= W - 1) ? 0.f : lax0) + ((lx >= 0) ? 0.f : lax1);
    const float w1l  = ((lx >= W - 1) ? lax0 : 0.f) + ((lx >= 0) ? lax1 : 0.f);
    const int   loA  = min(max(ly, 0), H - 1) * (W * 4) + min(max(lx, 0), W - 2) * 4;
    const int   loB  = min(max(ly + 1, 0), H - 1) * (W * 4) + min(max(lx, 0), W - 2) * 4;
    const float lwy0 = ((unsigned)ly       < (unsigned)H) ? (1.0f - fy) : 0.0f;
    const float lwy1 = ((unsigned)(ly + 1) < (unsigned)H) ? fy : 0.0f;

    const char* RbC = (const char*)(rfeat + (size_t)(lvl * NCH) * HW);
    const char* LbC = (const char*)(lfeat + (size_t)(lvl * NCH) * HW);

    float acc = 0.0f;
#pragma unroll 1
    for (int c = 0; c < NCH; c += 2) {
        const char* RpC0 = RbC + (size_t)c * HW * 4;
        const char* RpC1 = RpC0 + (size_t)HW * 4;
        const char* LpC0 = LbC + (size_t)c * HW * 4;
        const char* LpC1 = LpC0 + (size_t)HW * 4;

        if (!isP0) {
            // ---- pass-1 strip: y-row rotation (6 row-loads, not 10) ----
            int rbp = min(max(y0i - 2, 0), H - 1) * (W * 4);   // raw row r=0
            F2 a0 = LOADF2(RpC0 + rbp, pairB);
            F2 a1 = LOADF2(RpC1 + rbp, pairB);
            float h0p = fmaf(w0, a0.x, w1 * a0.y);
            float h1p = fmaf(w0, a1.x, w1 * a1.y);
#pragma unroll 1
            for (int yy = 0; yy < 5; ++yy) {
                int   yrc = y0i + yy - 1;                      // raw row r=yy+1
                int   rbc = min(max(yrc, 0), H - 1) * (W * 4);
                F2 c0 = LOADF2(RpC0 + rbc, pairB);
                F2 c1 = LOADF2(RpC1 + rbc, pairB);
                float h0c = fmaf(w0, c0.x, w1 * c0.y);
                float h1c = fmaf(w0, c1.x, w1 * c1.y);
                int   yr  = y0i + yy - 2;
                float wy0 = ((unsigned)yr  < (unsigned)H) ? (1.0f - fy) : 0.0f;
                float wy1 = ((unsigned)yrc < (unsigned)H) ? fy : 0.0f;
                svh[wv][yy][l] = U32(__floats2half2_rn(fmaf(wy0, h0p, wy1 * h0c),
                                                       fmaf(wy0, h1p, wy1 * h1c)));
                h0p = h0c; h1p = h1c;
            }
            // cleanup cols 64-67 (lanes<20)
            if (l < 20) {
                F2 pa0 = LOADF2(RpC0, voA);
                F2 pb0 = LOADF2(RpC0, voB);
                F2 pa1 = LOADF2(RpC1, voA);
                F2 pb1 = LOADF2(RpC1, voB);
                float h00 = fmaf(w0d, pa0.x, w1d * pa0.y);
                float h01 = fmaf(w0d, pb0.x, w1d * pb0.y);
                float h10 = fmaf(w0d, pa1.x, w1d * pa1.y);
                float h11 = fmaf(w0d, pb1.x, w1d * pb1.y);
                svh[wv][dyc][dcol] = U32(__floats2half2_rn(fmaf(dwy0, h00, dwy1 * h01),
                                                           fmaf(dwy0, h10, dwy1 * h11)));
            }
        } else if (l < 52) {
            // ---- pass-0 strip: s=4, rows disjoint -> old 4-load rows ----
#pragma unroll 1
            for (int yy = 0; yy < 5; ++yy) {
                int   yr   = y0i + 4 * (yy - 2);
                int   rbB0 = min(max(yr, 0), H - 1) * (W * 4);
                int   rbB1 = min(max(yr + 1, 0), H - 1) * (W * 4);
                float wy0  = ((unsigned)yr       < (unsigned)H) ? (1.0f - fy) : 0.0f;
                float wy1  = ((unsigned)(yr + 1) < (unsigned)H) ? fy : 0.0f;
                F2 a0 = LOADF2(RpC0 + rbB0, pairB);
                F2 b0 = LOADF2(RpC0 + rbB1, pairB);
                F2 a1 = LOADF2(RpC1 + rbB0, pairB);
                F2 b1 = LOADF2(RpC1 + rbB1, pairB);
                float h00 = fmaf(w0, a0.x, w1 * a0.y);
                float h01 = fmaf(w0, b0.x, w1 * b0.y);
                float h10 = fmaf(w0, a1.x, w1 * a1.y);
                float h11 = fmaf(w0, b1.x, w1 * b1.y);
                svh[wv][yy][l] = U32(__floats2half2_rn(fmaf(wy0, h00, wy1 * h01),
                                                       fmaf(wy0, h10, wy1 * h11)));
            }
        }

        unsigned lpk;
        {
            F2 pa0 = LOADF2(LpC0, loA);
            F2 pb0 = LOADF2(LpC0, loB);
            F2 pa1 = LOADF2(LpC1, loA);
            F2 pb1 = LOADF2(LpC1, loB);
            float h00 = fmaf(w0l, pa0.x, w1l * pa0.y);
            float h01 = fmaf(w0l, pb0.x, w1l * pb0.y);
            float h10 = fmaf(w0l, pa1.x, w1l * pa1.y);
            float h11 = fmaf(w0l, pb1.x, w1l * pb1.y);
            float lval0 = fmaf(lwy0, h00, lwy1 * h01);
            float lval1 = fmaf(lwy0, h10, lwy1 * h11);
            lpk = U32(__floats2half2_rn(lval0, lval1));
        }

        if (l < DC) {
            __half2 aE = __floats2half2_rn(0.f, 0.f);
            __half2 aO = __floats2half2_rn(0.f, 0.f);
#define TAPROW(YY) {                                                        \
            const unsigned* rp = &svh[wv][YY][DC - 1 - l];                  \
            unsigned q0 = rp[0], q1 = rp[1], q2 = rp[2], q3 = rp[3], q4 = rp[4];\
            unsigned s0 = RDLU(lpk, (YY)*5+0);                              \
            unsigned s1 = RDLU(lpk, (YY)*5+1);                              \
            unsigned s2 = RDLU(lpk, (YY)*5+2);                              \
            unsigned s3 = RDLU(lpk, (YY)*5+3);                              \
            unsigned s4 = RDLU(lpk, (YY)*5+4);                              \
            aE = __hadd2(aE, __habs2(__hsub2(H2(s0), H2(q0))));             \
            aO = __hadd2(aO, __habs2(__hsub2(H2(s1), H2(q1))));             \
            aE = __hadd2(aE, __habs2(__hsub2(H2(s2), H2(q2))));             \
            aO = __hadd2(aO, __habs2(__hsub2(H2(s3), H2(q3))));             \
            aE = __hadd2(aE, __habs2(__hsub2(H2(s4), H2(q4)))); }
            TAPROW(0)
            TAPROW(1)
            TAPROW(2)
            TAPROW(3)
            TAPROW(4)
#undef TAPROW
            __half2 at = __hadd2(aE, aO);
            acc += __half2float(__low2half(at)) + __half2float(__high2half(at));
        }
    }

    if (isP0 && l < 48)
        val4[l] = 1.0f - expf(-acc * (1.0f / 400.0f));

    __syncthreads();                     // the ONLY block-wide barrier

    if (tid < MAXD) {                    // waves 0-2: d == tid
        float v1  = 1.0f - expf(-acc * (1.0f / 400.0f));
        float pos = (float)tid * (47.0f / 191.0f);
        float i0f = floorf(pos);
        int   i0  = (int)i0f;
        float w   = pos - i0f;
        int   i1  = min(i0 + 1, 47);
        float up  = val4[i0] + w * (val4[i1] - val4[i0]);
        out[((size_t)n * MAXD + tid) * 8 + j] = v1 + up;
    }
}

extern "C" void kernel_launch(void* const* d_in, const int* in_sizes, int n_in,
                              void* d_out, int out_size, void* d_ws, size_t ws_size,
                              hipStream_t stream) {
    const float* lf  = (const float*)d_in[0];
    const float* rf  = (const float*)d_in[1];
    const float* pts = (const float*)d_in[2];
    const int*   pW  = (const int*)d_in[3];
    const int*   pH  = (const int*)d_in[4];
    float* out = (float*)d_out;

    const int N = in_sizes[2] / 2;       // (B=1, N, 2)
    pbm_kernel<<<dim3(8, N), 256, 0, stream>>>(lf, rf, pts, pW, pH, out);
}

// Round 19
// 149.891 us; speedup vs baseline: 3.3226x; 1.1410x over previous
//
#include <hip/hip_runtime.h>
#include <hip/hip_fp16.h>

#define MAXD 192
#define NCH  16

#define RFL_I(x) __builtin_amdgcn_readfirstlane(x)
#define RFL_F(x) __int_as_float(__builtin_amdgcn_readfirstlane(__float_as_int(x)))
#define RDLU(v,k) ((unsigned)__builtin_amdgcn_readlane((int)(v), (k)))
#define H2(u) __builtin_bit_cast(__half2, (unsigned)(u))
#define U32(h) __builtin_bit_cast(unsigned, (h))
#define BPERM(idx, v) __int_as_float(__builtin_amdgcn_ds_bpermute((idx), __float_as_int(v)))

struct F2 { float x, y; };   // align 4: dword-aligned global pair load
#define LOADF2(base, boff) (*(const F2*)((base) + (boff)))

// One block per (level j = blockIdx.x, point n = blockIdx.y) — XCD = j.
// Waves 0-2: pass-1 (scale 1) disparity chunks; wave 3: pass-0 (scale 4).
// R19: further VMEM-instruction cuts (R10/R18 proved ~10cyc/instr marginal):
//  - cleanup (pass-1): row-rotation over lanes 0-23 (6 rows x 4 cols), one
//    row-load per lane (2 VMEM, was 4); y-neighbor via ds_bpermute(l+4).
//  - left window: 6-stride lane layout (lane = r*6+c). Pass-1: one raw row
//    per lane (2 VMEM, was 4), y-neighbor via bpermute(+6). Pass-0: 10 raw
//    rows x 6 cols in 60 lanes (2 VMEM, was 4), taps via 2 bpermutes
//    (src 12r+c, +6). Out-of-role lanes clamp to fetched addrs (junk unused).
//  - TAPROW readlane stride 5 -> 6.
// All bperm sources computed UNGUARDED (all 64 lanes valid).
// Strip paths unchanged from R18 (pass-1 y-rotation, pass-0 classic).
// LESSON: no big register arrays / no unrolling (spills); WRITE_SIZE is
// the spill tripwire (~49 MB).
__global__ __launch_bounds__(256, 8) void pbm_kernel(
    const float* __restrict__ lfeat,   // (16,1,16,H,W)
    const float* __restrict__ rfeat,
    const float* __restrict__ points,  // (1,N,2)
    const int* __restrict__ pW, const int* __restrict__ pH,
    float* __restrict__ out)           // (1,N,192,8)
{
    const int W = RFL_I(*pW), H = RFL_I(*pH);
    const int HW = W * H;
    const int j   = blockIdx.x;        // XCD = j
    const int n   = blockIdx.y;
    const int tid = threadIdx.x;
    const int wv  = tid >> 6;
    const int l   = tid & 63;

    const float pxr = points[2 * n];
    const float pyr = points[2 * n + 1];
    const float pxf = floorf(pxr), pyf = floorf(pyr);
    const float fx  = RFL_F(pxr - pxf);
    const float fy  = RFL_F(pyr - pyf);
    const int   x0i = RFL_I((int)pxf);
    const int   y0i = RFL_I((int)pyf);

    __shared__ unsigned svh[4][5][68]; // per-wave right strip, half2 (2 ch packed)
    __shared__ float    val4[48];

    const bool isP0   = (wv == 3);
    const int  s_     = RFL_I(isP0 ? 4 : 1);
    const int  lvl    = RFL_I(isP0 ? j + 8 : j);
    const int  off    = RFL_I(isP0 ? 49 : wv * 64 + 65);
    const int  DC     = RFL_I(isP0 ? 48 : 64);

    // ---- strip column constants (col == lane): pair offset + folded weights
    const int   cx    = x0i + s_ * (l - off);
    const int   pairB = min(max(cx, 0), W - 2) * 4;
    const float ax0   = (((unsigned)cx       < (unsigned)W) ? 1.0f : 0.0f) * (1.0f - fx);
    const float ax1   = (((unsigned)(cx + 1) < (unsigned)W) ? 1.0f : 0.0f) * fx;
    const float w0    = ((cx >= W - 1) ? 0.f : ax0) + ((cx >= 0) ? 0.f : ax1);
    const float w1    = ((cx >= W - 1) ? ax0 : 0.f) + ((cx >= 0) ? ax1 : 0.f);

    // ---- cleanup (pass-1): lanes 0-23 = (raw row min(l>>2,5)) x (col l&3) ----
    const int   dcx  = x0i + (64 + (l & 3)) - off;          // s=1 only
    const float dax0 = (((unsigned)dcx       < (unsigned)W) ? 1.0f : 0.0f) * (1.0f - fx);
    const float dax1 = (((unsigned)(dcx + 1) < (unsigned)W) ? 1.0f : 0.0f) * fx;
    const float w0d  = ((dcx >= W - 1) ? 0.f : dax0) + ((dcx >= 0) ? 0.f : dax1);
    const float w1d  = ((dcx >= W - 1) ? dax0 : 0.f) + ((dcx >= 0) ? dax1 : 0.f);
    const int   voS  = min(max(y0i + min(l >> 2, 5) - 2, 0), H - 1) * (W * 4)
                     + min(max(dcx, 0), W - 2) * 4;
    const int   dyr  = y0i + min(l >> 2, 4) - 2;            // dest-row weights
    const float dwy0 = ((unsigned)dyr       < (unsigned)H) ? (1.0f - fy) : 0.0f;
    const float dwy1 = ((unsigned)(dyr + 1) < (unsigned)H) ? fy : 0.0f;

    // ---- left window, 6-stride layout: dest tap lane = rd*6+cd ----
    const int   lq = min(l, 35);
    const int   rd = lq / 6;
    const int   cd = lq - rd * 6;
    int lrow, lcx;
    if (isP0) {                       // load-lane mapping (wave-uniform branch)
        int ls = min(l, 59);
        int ri = ls / 6, cc = ls - ri * 6;
        lrow = y0i + 4 * ((ri >> 1) - 2) + (ri & 1);        // 10 raw rows
        lcx  = x0i + 4 * (min(cc, 4) - 2);                  // clamp col: fetch-neutral
    } else {
        lrow = y0i + rd - 2;                                // 6 raw rows
        lcx  = x0i + cd - 2;
    }
    const int   loS  = min(max(lrow, 0), H - 1) * (W * 4) + min(max(lcx, 0), W - 2) * 4;
    const float gx0  = (((unsigned)lcx       < (unsigned)W) ? 1.0f : 0.0f) * (1.0f - fx);
    const float gx1  = (((unsigned)(lcx + 1) < (unsigned)W) ? 1.0f : 0.0f) * fx;
    const float lv0  = ((lcx >= W - 1) ? 0.f : gx0) + ((lcx >= 0) ? 0.f : gx1);
    const float lv1  = ((lcx >= W - 1) ? gx0 : 0.f) + ((lcx >= 0) ? gx1 : 0.f);
    const int   ib0  = isP0 ? (12 * rd + cd) * 4 : (l * 4);
    const int   ib1  = isP0 ? ((12 * rd + cd) * 4 + 24) : ((l + 6) * 4);
    const int   lyd  = y0i + s_ * (rd - 2);
    const float lwy0 = ((unsigned)lyd       < (unsigned)H) ? (1.0f - fy) : 0.0f;
    const float lwy1 = ((unsigned)(lyd + 1) < (unsigned)H) ? fy : 0.0f;

    const char* RbC = (const char*)(rfeat + (size_t)(lvl * NCH) * HW);
    const char* LbC = (const char*)(lfeat + (size_t)(lvl * NCH) * HW);

    float acc = 0.0f;
#pragma unroll 1
    for (int c = 0; c < NCH; c += 2) {
        const char* RpC0 = RbC + (size_t)c * HW * 4;
        const char* RpC1 = RpC0 + (size_t)HW * 4;
        const char* LpC0 = LbC + (size_t)c * HW * 4;
        const char* LpC1 = LpC0 + (size_t)HW * 4;

        if (!isP0) {
            // ---- pass-1 strip: y-row rotation (6 row-loads, not 10) ----
            int rbp = min(max(y0i - 2, 0), H - 1) * (W * 4);
            F2 a0 = LOADF2(RpC0 + rbp, pairB);
            F2 a1 = LOADF2(RpC1 + rbp, pairB);
            float h0p = fmaf(w0, a0.x, w1 * a0.y);
            float h1p = fmaf(w0, a1.x, w1 * a1.y);
#pragma unroll 1
            for (int yy = 0; yy < 5; ++yy) {
                int   yrc = y0i + yy - 1;
                int   rbc = min(max(yrc, 0), H - 1) * (W * 4);
                F2 c0 = LOADF2(RpC0 + rbc, pairB);
                F2 c1 = LOADF2(RpC1 + rbc, pairB);
                float h0c = fmaf(w0, c0.x, w1 * c0.y);
                float h1c = fmaf(w0, c1.x, w1 * c1.y);
                int   yr  = y0i + yy - 2;
                float wy0 = ((unsigned)yr  < (unsigned)H) ? (1.0f - fy) : 0.0f;
                float wy1 = ((unsigned)yrc < (unsigned)H) ? fy : 0.0f;
                svh[wv][yy][l] = U32(__floats2half2_rn(fmaf(wy0, h0p, wy1 * h0c),
                                                       fmaf(wy0, h1p, wy1 * h1c)));
                h0p = h0c; h1p = h1c;
            }
            // ---- cleanup rotation: 1 row-load/channel + bpermute(+4) ----
            {
                F2 e0 = LOADF2(RpC0, voS);
                F2 e1 = LOADF2(RpC1, voS);
                float g0 = fmaf(w0d, e0.x, w1d * e0.y);
                float g1 = fmaf(w0d, e1.x, w1d * e1.y);
                float g0n = BPERM((l + 4) * 4, g0);
                float g1n = BPERM((l + 4) * 4, g1);
                if (l < 20)
                    svh[wv][l >> 2][64 + (l & 3)] =
                        U32(__floats2half2_rn(fmaf(dwy0, g0, dwy1 * g0n),
                                              fmaf(dwy0, g1, dwy1 * g1n)));
            }
        } else if (l < 52) {
            // ---- pass-0 strip: s=4, rows disjoint -> classic 4-load rows ----
#pragma unroll 1
            for (int yy = 0; yy < 5; ++yy) {
                int   yr   = y0i + 4 * (yy - 2);
                int   rbB0 = min(max(yr, 0), H - 1) * (W * 4);
                int   rbB1 = min(max(yr + 1, 0), H - 1) * (W * 4);
                float wy0  = ((unsigned)yr       < (unsigned)H) ? (1.0f - fy) : 0.0f;
                float wy1  = ((unsigned)(yr + 1) < (unsigned)H) ? fy : 0.0f;
                F2 a0 = LOADF2(RpC0 + rbB0, pairB);
                F2 b0 = LOADF2(RpC0 + rbB1, pairB);
                F2 a1 = LOADF2(RpC1 + rbB0, pairB);
                F2 b1 = LOADF2(RpC1 + rbB1, pairB);
                float h00 = fmaf(w0, a0.x, w1 * a0.y);
                float h01 = fmaf(w0, b0.x, w1 * b0.y);
                float h10 = fmaf(w0, a1.x, w1 * a1.y);
                float h11 = fmaf(w0, b1.x, w1 * b1.y);
                svh[wv][yy][l] = U32(__floats2half2_rn(fmaf(wy0, h00, wy1 * h01),
                                                       fmaf(wy0, h10, wy1 * h11)));
            }
        }

        // ---- left window: 1 pair-load/channel + 2 bpermutes ----
        unsigned lpk;
        {
            F2 p0 = LOADF2(LpC0, loS);
            F2 p1 = LOADF2(LpC1, loS);
            float h0 = fmaf(lv0, p0.x, lv1 * p0.y);
            float h1 = fmaf(lv0, p1.x, lv1 * p1.y);
            float a0 = BPERM(ib0, h0), b0 = BPERM(ib1, h0);
            float a1 = BPERM(ib0, h1), b1 = BPERM(ib1, h1);
            lpk = U32(__floats2half2_rn(fmaf(lwy0, a0, lwy1 * b0),
                                        fmaf(lwy0, a1, lwy1 * b1)));
        }

        if (l < DC) {
            __half2 aE = __floats2half2_rn(0.f, 0.f);
            __half2 aO = __floats2half2_rn(0.f, 0.f);
#define TAPROW(YY) {                                                        \
            const unsigned* rp = &svh[wv][YY][DC - 1 - l];                  \
            unsigned q0 = rp[0], q1 = rp[1], q2 = rp[2], q3 = rp[3], q4 = rp[4];\
            unsigned s0 = RDLU(lpk, (YY)*6+0);                              \
            unsigned s1 = RDLU(lpk, (YY)*6+1);                              \
            unsigned s2 = RDLU(lpk, (YY)*6+2);                              \
            unsigned s3 = RDLU(lpk, (YY)*6+3);                              \
            unsigned s4 = RDLU(lpk, (YY)*6+4);                              \
            aE = __hadd2(aE, __habs2(__hsub2(H2(s0), H2(q0))));             \
            aO = __hadd2(aO, __habs2(__hsub2(H2(s1), H2(q1))));             \
            aE = __hadd2(aE, __habs2(__hsub2(H2(s2), H2(q2))));             \
            aO = __hadd2(aO, __habs2(__hsub2(H2(s3), H2(q3))));             \
            aE = __hadd2(aE, __habs2(__hsub2(H2(s4), H2(q4)))); }
            TAPROW(0)
            TAPROW(1)
            TAPROW(2)
            TAPROW(3)
            TAPROW(4)
#undef TAPROW
            __half2 at = __hadd2(aE, aO);
            acc += __half2float(__low2half(at)) + __half2float(__high2half(at));
        }
    }

    if (isP0 && l < 48)
        val4[l] = 1.0f - expf(-acc * (1.0f / 400.0f));

    __syncthreads();                     // the ONLY block-wide barrier

    if (tid < MAXD) {                    // waves 0-2: d == tid
        float v1  = 1.0f - expf(-acc * (1.0f / 400.0f));
        float pos = (float)tid * (47.0f / 191.0f);
        float i0f = floorf(pos);
        int   i0  = (int)i0f;
        float w   = pos - i0f;
        int   i1  = min(i0 + 1, 47);
        float up  = val4[i0] + w * (val4[i1] - val4[i0]);
        out[((size_t)n * MAXD + tid) * 8 + j] = v1 + up;
    }
}

extern "C" void kernel_launch(void* const* d_in, const int* in_sizes, int n_in,
                              void* d_out, int out_size, void* d_ws, size_t ws_size,
                              hipStream_t stream) {
    const float* lf  = (const float*)d_in[0];
    const float* rf  = (const float*)d_in[1];
    const float* pts = (const float*)d_in[2];
    const int*   pW  = (const int*)d_in[3];
    const int*   pH  = (const int*)d_in[4];
    float* out = (float*)d_out;

    const int N = in_sizes[2] / 2;       // (B=1, N, 2)
    pbm_kernel<<<dim3(8, N), 256, 0, stream>>>(lf, rf, pts, pW, pH, out);
}

// Round 20
// 145.224 us; speedup vs baseline: 3.4293x; 1.0321x over previous
//
#include <hip/hip_runtime.h>
#include <hip/hip_fp16.h>

#define MAXD 192
#define NCH  16

#define RFL_I(x) __builtin_amdgcn_readfirstlane(x)
#define RFL_F(x) __int_as_float(__builtin_amdgcn_readfirstlane(__float_as_int(x)))
#define RDLU(v,k) ((unsigned)__builtin_amdgcn_readlane((int)(v), (k)))
#define H2(u) __builtin_bit_cast(__half2, (unsigned)(u))
#define U32(h) __builtin_bit_cast(unsigned, (h))
#define BPERM(idx, v) __int_as_float(__builtin_amdgcn_ds_bpermute((idx), __float_as_int(v)))

struct F2 { float x, y; };   // align 4: dword-aligned global pair load
#define LOADF2(base, boff) (*(const F2*)((base) + (boff)))

// One block per (level j = blockIdx.x, point n = blockIdx.y) — XCD = j.
// Waves 0-2: pass-1 (scale 1) disparity chunks; wave 3: pass-0 (scale 4).
// R20 (on R19): ILP within the iteration —
//  (1) cleanup + left-window loads FRONT-LOADED before the strip loop so
//      their latency hides under the 6-row strip work;
//  (2) strip row loops unroll 2 (4 loads in flight; rotation carry kept).
// R19 recap: VMEM-instr-minimal staging (row rotation, bpermute cleanup +
// left window, 6-stride tap layout), packed half2 strip, pk-f16 taps.
// LESSON: no big register arrays / no channel-loop unrolling (spills);
// WRITE_SIZE is the spill tripwire (~49 MB).
__global__ __launch_bounds__(256, 8) void pbm_kernel(
    const float* __restrict__ lfeat,   // (16,1,16,H,W)
    const float* __restrict__ rfeat,
    const float* __restrict__ points,  // (1,N,2)
    const int* __restrict__ pW, const int* __restrict__ pH,
    float* __restrict__ out)           // (1,N,192,8)
{
    const int W = RFL_I(*pW), H = RFL_I(*pH);
    const int HW = W * H;
    const int j   = blockIdx.x;        // XCD = j
    const int n   = blockIdx.y;
    const int tid = threadIdx.x;
    const int wv  = tid >> 6;
    const int l   = tid & 63;

    const float pxr = points[2 * n];
    const float pyr = points[2 * n + 1];
    const float pxf = floorf(pxr), pyf = floorf(pyr);
    const float fx  = RFL_F(pxr - pxf);
    const float fy  = RFL_F(pyr - pyf);
    const int   x0i = RFL_I((int)pxf);
    const int   y0i = RFL_I((int)pyf);

    __shared__ unsigned svh[4][5][68]; // per-wave right strip, half2 (2 ch packed)
    __shared__ float    val4[48];

    const bool isP0   = (wv == 3);
    const int  s_     = RFL_I(isP0 ? 4 : 1);
    const int  lvl    = RFL_I(isP0 ? j + 8 : j);
    const int  off    = RFL_I(isP0 ? 49 : wv * 64 + 65);
    const int  DC     = RFL_I(isP0 ? 48 : 64);

    // ---- strip column constants (col == lane): pair offset + folded weights
    const int   cx    = x0i + s_ * (l - off);
    const int   pairB = min(max(cx, 0), W - 2) * 4;
    const float ax0   = (((unsigned)cx       < (unsigned)W) ? 1.0f : 0.0f) * (1.0f - fx);
    const float ax1   = (((unsigned)(cx + 1) < (unsigned)W) ? 1.0f : 0.0f) * fx;
    const float w0    = ((cx >= W - 1) ? 0.f : ax0) + ((cx >= 0) ? 0.f : ax1);
    const float w1    = ((cx >= W - 1) ? ax0 : 0.f) + ((cx >= 0) ? ax1 : 0.f);

    // ---- cleanup (pass-1): lanes 0-23 = (raw row min(l>>2,5)) x (col l&3) ----
    const int   dcx  = x0i + (64 + (l & 3)) - off;          // s=1 only
    const float dax0 = (((unsigned)dcx       < (unsigned)W) ? 1.0f : 0.0f) * (1.0f - fx);
    const float dax1 = (((unsigned)(dcx + 1) < (unsigned)W) ? 1.0f : 0.0f) * fx;
    const float w0d  = ((dcx >= W - 1) ? 0.f : dax0) + ((dcx >= 0) ? 0.f : dax1);
    const float w1d  = ((dcx >= W - 1) ? dax0 : 0.f) + ((dcx >= 0) ? dax1 : 0.f);
    const int   voS  = min(max(y0i + min(l >> 2, 5) - 2, 0), H - 1) * (W * 4)
                     + min(max(dcx, 0), W - 2) * 4;
    const int   dyr  = y0i + min(l >> 2, 4) - 2;            // dest-row weights
    const float dwy0 = ((unsigned)dyr       < (unsigned)H) ? (1.0f - fy) : 0.0f;
    const float dwy1 = ((unsigned)(dyr + 1) < (unsigned)H) ? fy : 0.0f;

    // ---- left window, 6-stride layout: dest tap lane = rd*6+cd ----
    const int   lq = min(l, 35);
    const int   rd = lq / 6;
    const int   cd = lq - rd * 6;
    int lrow, lcx;
    if (isP0) {                       // load-lane mapping (wave-uniform branch)
        int ls = min(l, 59);
        int ri = ls / 6, cc = ls - ri * 6;
        lrow = y0i + 4 * ((ri >> 1) - 2) + (ri & 1);        // 10 raw rows
        lcx  = x0i + 4 * (min(cc, 4) - 2);                  // clamp col: fetch-neutral
    } else {
        lrow = y0i + rd - 2;                                // 6 raw rows
        lcx  = x0i + cd - 2;
    }
    const int   loS  = min(max(lrow, 0), H - 1) * (W * 4) + min(max(lcx, 0), W - 2) * 4;
    const float gx0  = (((unsigned)lcx       < (unsigned)W) ? 1.0f : 0.0f) * (1.0f - fx);
    const float gx1  = (((unsigned)(lcx + 1) < (unsigned)W) ? 1.0f : 0.0f) * fx;
    const float lv0  = ((lcx >= W - 1) ? 0.f : gx0) + ((lcx >= 0) ? 0.f : gx1);
    const float lv1  = ((lcx >= W - 1) ? gx0 : 0.f) + ((lcx >= 0) ? gx1 : 0.f);
    const int   ib0  = isP0 ? (12 * rd + cd) * 4 : (l * 4);
    const int   ib1  = isP0 ? ((12 * rd + cd) * 4 + 24) : ((l + 6) * 4);
    const int   lyd  = y0i + s_ * (rd - 2);
    const float lwy0 = ((unsigned)lyd       < (unsigned)H) ? (1.0f - fy) : 0.0f;
    const float lwy1 = ((unsigned)(lyd + 1) < (unsigned)H) ? fy : 0.0f;

    const char* RbC = (const char*)(rfeat + (size_t)(lvl * NCH) * HW);
    const char* LbC = (const char*)(lfeat + (size_t)(lvl * NCH) * HW);

    float acc = 0.0f;
#pragma unroll 1
    for (int c = 0; c < NCH; c += 2) {
        const char* RpC0 = RbC + (size_t)c * HW * 4;
        const char* RpC1 = RpC0 + (size_t)HW * 4;
        const char* LpC0 = LbC + (size_t)c * HW * 4;
        const char* LpC1 = LpC0 + (size_t)HW * 4;

        // ---- FRONT-LOADED independent loads (latency hides under strip) ----
        F2 e0 = LOADF2(RpC0, voS);      // cleanup row (pass-1 meaningful)
        F2 e1 = LOADF2(RpC1, voS);
        F2 p0 = LOADF2(LpC0, loS);      // left-window row
        F2 p1 = LOADF2(LpC1, loS);

        if (!isP0) {
            // ---- pass-1 strip: y-row rotation (6 row-loads), unroll 2 ----
            int rbp = min(max(y0i - 2, 0), H - 1) * (W * 4);
            F2 a0 = LOADF2(RpC0 + rbp, pairB);
            F2 a1 = LOADF2(RpC1 + rbp, pairB);
            float h0p = fmaf(w0, a0.x, w1 * a0.y);
            float h1p = fmaf(w0, a1.x, w1 * a1.y);
#pragma unroll 2
            for (int yy = 0; yy < 5; ++yy) {
                int   yrc = y0i + yy - 1;
                int   rbc = min(max(yrc, 0), H - 1) * (W * 4);
                F2 c0 = LOADF2(RpC0 + rbc, pairB);
                F2 c1 = LOADF2(RpC1 + rbc, pairB);
                float h0c = fmaf(w0, c0.x, w1 * c0.y);
                float h1c = fmaf(w0, c1.x, w1 * c1.y);
                int   yr  = y0i + yy - 2;
                float wy0 = ((unsigned)yr  < (unsigned)H) ? (1.0f - fy) : 0.0f;
                float wy1 = ((unsigned)yrc < (unsigned)H) ? fy : 0.0f;
                svh[wv][yy][l] = U32(__floats2half2_rn(fmaf(wy0, h0p, wy1 * h0c),
                                                       fmaf(wy0, h1p, wy1 * h1c)));
                h0p = h0c; h1p = h1c;
            }
            // ---- cleanup rotation: lerp + bpermute(+4) on front-loaded e ----
            {
                float g0 = fmaf(w0d, e0.x, w1d * e0.y);
                float g1 = fmaf(w0d, e1.x, w1d * e1.y);
                float g0n = BPERM((l + 4) * 4, g0);
                float g1n = BPERM((l + 4) * 4, g1);
                if (l < 20)
                    svh[wv][l >> 2][64 + (l & 3)] =
                        U32(__floats2half2_rn(fmaf(dwy0, g0, dwy1 * g0n),
                                              fmaf(dwy0, g1, dwy1 * g1n)));
            }
        } else if (l < 52) {
            // ---- pass-0 strip: s=4, rows disjoint -> classic rows, unroll 2 ----
#pragma unroll 2
            for (int yy = 0; yy < 5; ++yy) {
                int   yr   = y0i + 4 * (yy - 2);
                int   rbB0 = min(max(yr, 0), H - 1) * (W * 4);
                int   rbB1 = min(max(yr + 1, 0), H - 1) * (W * 4);
                float wy0  = ((unsigned)yr       < (unsigned)H) ? (1.0f - fy) : 0.0f;
                float wy1  = ((unsigned)(yr + 1) < (unsigned)H) ? fy : 0.0f;
                F2 a0 = LOADF2(RpC0 + rbB0, pairB);
                F2 b0 = LOADF2(RpC0 + rbB1, pairB);
                F2 a1 = LOADF2(RpC1 + rbB0, pairB);
                F2 b1 = LOADF2(RpC1 + rbB1, pairB);
                float h00 = fmaf(w0, a0.x, w1 * a0.y);
                float h01 = fmaf(w0, b0.x, w1 * b0.y);
                float h10 = fmaf(w0, a1.x, w1 * a1.y);
                float h11 = fmaf(w0, b1.x, w1 * b1.y);
                svh[wv][yy][l] = U32(__floats2half2_rn(fmaf(wy0, h00, wy1 * h01),
                                                       fmaf(wy0, h10, wy1 * h11)));
            }
        }

        // ---- left window: lerp + 2 bpermutes on front-loaded p ----
        unsigned lpk;
        {
            float h0 = fmaf(lv0, p0.x, lv1 * p0.y);
            float h1 = fmaf(lv0, p1.x, lv1 * p1.y);
            float a0 = BPERM(ib0, h0), b0 = BPERM(ib1, h0);
            float a1 = BPERM(ib0, h1), b1 = BPERM(ib1, h1);
            lpk = U32(__floats2half2_rn(fmaf(lwy0, a0, lwy1 * b0),
                                        fmaf(lwy0, a1, lwy1 * b1)));
        }

        if (l < DC) {
            __half2 aE = __floats2half2_rn(0.f, 0.f);
            __half2 aO = __floats2half2_rn(0.f, 0.f);
#define TAPROW(YY) {                                                        \
            const unsigned* rp = &svh[wv][YY][DC - 1 - l];                  \
            unsigned q0 = rp[0], q1 = rp[1], q2 = rp[2], q3 = rp[3], q4 = rp[4];\
            unsigned s0 = RDLU(lpk, (YY)*6+0);                              \
            unsigned s1 = RDLU(lpk, (YY)*6+1);                              \
            unsigned s2 = RDLU(lpk, (YY)*6+2);                              \
            unsigned s3 = RDLU(lpk, (YY)*6+3);                              \
            unsigned s4 = RDLU(lpk, (YY)*6+4);                              \
            aE = __hadd2(aE, __habs2(__hsub2(H2(s0), H2(q0))));             \
            aO = __hadd2(aO, __habs2(__hsub2(H2(s1), H2(q1))));             \
            aE = __hadd2(aE, __habs2(__hsub2(H2(s2), H2(q2))));             \
            aO = __hadd2(aO, __habs2(__hsub2(H2(s3), H2(q3))));             \
            aE = __hadd2(aE, __habs2(__hsub2(H2(s4), H2(q4)))); }
            TAPROW(0)
            TAPROW(1)
            TAPROW(2)
            TAPROW(3)
            TAPROW(4)
#undef TAPROW
            __half2 at = __hadd2(aE, aO);
            acc += __half2float(__low2half(at)) + __half2float(__high2half(at));
        }
    }

    if (isP0 && l < 48)
        val4[l] = 1.0f - expf(-acc * (1.0f / 400.0f));

    __syncthreads();                     // the ONLY block-wide barrier

    if (tid < MAXD) {                    // waves 0-2: d == tid
        float v1  = 1.0f - expf(-acc * (1.0f / 400.0f));
        float pos = (float)tid * (47.0f / 191.0f);
        float i0f = floorf(pos);
        int   i0  = (int)i0f;
        float w   = pos - i0f;
        int   i1  = min(i0 + 1, 47);
        float up  = val4[i0] + w * (val4[i1] - val4[i0]);
        out[((size_t)n * MAXD + tid) * 8 + j] = v1 + up;
    }
}

extern "C" void kernel_launch(void* const* d_in, const int* in_sizes, int n_in,
                              void* d_out, int out_size, void* d_ws, size_t ws_size,
                              hipStream_t stream) {
    const float* lf  = (const float*)d_in[0];
    const float* rf  = (const float*)d_in[1];
    const float* pts = (const float*)d_in[2];
    const int*   pW  = (const int*)d_in[3];
    const int*   pH  = (const int*)d_in[4];
    float* out = (float*)d_out;

    const int N = in_sizes[2] / 2;       // (B=1, N, 2)
    pbm_kernel<<<dim3(8, N), 256, 0, stream>>>(lf, rf, pts, pW, pH, out);
}